// Round 7
// baseline (504.006 us; speedup 1.0000x reference)
//
#include <hip/hip_runtime.h>

// Problem constants (match reference)
#define D    128      // embedding dim
#define VSZ  200000   // vocab (emb has VSZ+1 rows, last row = 0)
#define NB   4096     // batch B
#define MM   50       // neighbors
#define DM   256      // 2*D
#define HSZ  512      // H
#define G4   2048     // 4*H

typedef __attribute__((ext_vector_type(8))) short short8;   // 8 bf16 = 4 VGPRs
typedef __attribute__((ext_vector_type(4))) float floatx4;  // MFMA acc

__device__ __forceinline__ float sigf(float x) { return 1.0f / (1.0f + __expf(-x)); }
__device__ __forceinline__ float tanhfast(float x) { return 1.0f - 2.0f / (__expf(2.0f * x) + 1.0f); }
__device__ __forceinline__ unsigned short f2bf(float x) {
    unsigned int u = __float_as_uint(x);
    u += 0x7FFFu + ((u >> 16) & 1u);   // round-to-nearest-even
    return (unsigned short)(u >> 16);
}
__device__ __forceinline__ float bf2f(unsigned short s) {
    return __uint_as_float(((unsigned int)s) << 16);
}

// ---------------------------------------------------------------------------
// Kernel 0 (merged): pack Wih (2048x256) + Whh[:, :256] fragment-linear bf16,
// gb = bih + bhh, and gcn_W -> Wb[n][k] bf16.
// ---------------------------------------------------------------------------
__global__ __launch_bounds__(256) void k_pack(
    const float* __restrict__ Wih, const float* __restrict__ Whh,
    const float* __restrict__ bih, const float* __restrict__ bhh,
    const float* __restrict__ gcn_W,
    unsigned short* __restrict__ Wihp, unsigned short* __restrict__ Whhp,
    float* __restrict__ gb, unsigned short* __restrict__ Wb)
{
    int idx = blockIdx.x * 256 + threadIdx.x;
    if (idx < 131072) {
        int ci = idx & 65535;
        int lane = ci & 63, rest = ci >> 6;
        int ks = rest & 7, tile = rest >> 3;
        int n = tile * 16 + (lane & 15), k = ks * 32 + (lane >> 4) * 8;
        const float* src = (idx < 65536) ? (Wih + (size_t)n * 256 + k)
                                         : (Whh + (size_t)n * 512 + k);
        unsigned short* dst = (idx < 65536) ? Wihp : Whhp;
        short8 o;
        #pragma unroll
        for (int j = 0; j < 8; ++j) o[j] = (short)f2bf(src[j]);
        *(short8*)(dst + (size_t)ci * 8) = o;
    } else if (idx < 131072 + 2048) {
        int i = idx - 131072;
        gb[i] = bih[i] + bhh[i];
    } else if (idx < 131072 + 2048 + 32768) {
        int i = idx - 131072 - 2048;
        int n = i >> 7, k = i & 127;
        float v = (n < 128) ? gcn_W[n * 256 + k] : gcn_W[(n - 128) * 256 + 128 + k];
        Wb[i] = f2bf(v);
    }
}

// ---------------------------------------------------------------------------
// Kernel 1: P = emb @ Wcat^T via bf16 MFMA — BARRIER-FREE wave-strip form.
// Each wave independently owns a 16-row strip (grid-stride).  A-fragments
// loaded directly from global fp32 (lane(nl,quad) reads 8 consecutive floats
// of row nl: 16 x 128B fully-used segments per load).  B (Wb, 64 KB) from
// L1/L2.  Epilogue transposes through a wave-PRIVATE LDS quadrant relying on
// same-wave in-order DS execution — zero __syncthreads in the whole kernel
// (round-6: 4 barriers/block left all pipes <13% busy, 1.6 TB/s).
// ---------------------------------------------------------------------------
__global__ __launch_bounds__(256) void k_proj_mfma(
    const float* __restrict__ emb, const unsigned short* __restrict__ Wb,
    const float* __restrict__ gcn_lb, const float* __restrict__ gcn_b,
    unsigned short* __restrict__ P1, unsigned short* __restrict__ P2, int nrows)
{
    __shared__ unsigned short S[4][16 * 264];   // per-wave C stage, 33.8 KB
    int t = threadIdx.x;
    int lane = t & 63, w = t >> 6;
    int nl = lane & 15, quad = lane >> 4;
    unsigned short* Sw = S[w];
    int nstrips = (nrows + 15) >> 4;
    int stride = gridDim.x * 4;

    for (int strip = blockIdx.x * 4 + w; strip < nstrips; strip += stride) {
        int v0 = strip * 16;
        int vrow = v0 + nl;
        bool vok = (vrow < nrows);
        const float* erow = emb + (size_t)vrow * D;

        floatx4 acc[16];
        #pragma unroll
        for (int nt = 0; nt < 16; ++nt) acc[nt] = (floatx4){0.f, 0.f, 0.f, 0.f};

        #pragma unroll
        for (int ks = 0; ks < 4; ++ks) {
            float4 a0 = make_float4(0.f, 0.f, 0.f, 0.f), a1 = a0;
            if (vok) {
                a0 = *(const float4*)(erow + ks * 32 + quad * 8);
                a1 = *(const float4*)(erow + ks * 32 + quad * 8 + 4);
            }
            short8 af;
            af[0] = (short)f2bf(a0.x); af[1] = (short)f2bf(a0.y);
            af[2] = (short)f2bf(a0.z); af[3] = (short)f2bf(a0.w);
            af[4] = (short)f2bf(a1.x); af[5] = (short)f2bf(a1.y);
            af[6] = (short)f2bf(a1.z); af[7] = (short)f2bf(a1.w);
            #pragma unroll
            for (int nt = 0; nt < 16; ++nt) {
                short8 bfr = *(const short8*)(Wb + (size_t)(nt * 16 + nl) * 128 + ks * 32 + quad * 8);
                acc[nt] = __builtin_amdgcn_mfma_f32_16x16x32_bf16(af, bfr, acc[nt], 0, 0, 0);
            }
        }

        // epilogue: transpose via wave-private LDS (in-order DS, no barrier)
        #pragma unroll
        for (int nt = 0; nt < 16; ++nt) {
            int col = nt * 16 + nl;
            float bias = (col < 128) ? (gcn_lb[col] + gcn_b[col]) : 0.f;
            #pragma unroll
            for (int reg = 0; reg < 4; ++reg)
                Sw[(quad * 4 + reg) * 264 + col] = f2bf(acc[nt][reg] + bias);
        }
        #pragma unroll
        for (int i = 0; i < 8; ++i) {
            int c = lane + 64 * i;           // 512 chunks: 16 rows x 32
            int row = c >> 5, c8 = c & 31;
            int v = v0 + row;
            if (v < nrows) {
                int4 val = *(const int4*)(Sw + row * 264 + c8 * 8);
                unsigned short* dst = (c8 < 16) ? (P1 + (size_t)v * D + c8 * 8)
                                                : (P2 + (size_t)v * D + (c8 - 16) * 8);
                *(int4*)dst = val;
            }
        }
    }
}

// ---------------------------------------------------------------------------
// Kernel 2: neighbor aggregation, both conn tables concurrently.
// ---------------------------------------------------------------------------
__global__ __launch_bounds__(256) void k_nbr(
    const int* __restrict__ query, const int* __restrict__ support,
    const int* __restrict__ q_l1, const int* __restrict__ q_l2,
    const int* __restrict__ q_r1, const int* __restrict__ q_r2,
    const int* __restrict__ s_l1, const int* __restrict__ s_l2,
    const int* __restrict__ s_r1, const int* __restrict__ s_r2,
    const unsigned short* __restrict__ P1, const unsigned short* __restrict__ P2,
    const float* __restrict__ emb,
    const float* __restrict__ attn_W, const float* __restrict__ attn_b,
    const float* __restrict__ gate_W, const float* __restrict__ gate_lb,
    const float* __restrict__ gate_b,
    float* __restrict__ qv, unsigned short* __restrict__ qvbf,
    float* __restrict__ sv)
{
    __shared__ unsigned short proj[2 * MM * 136];   // bf16, 27.2 KB
    __shared__ int rel[2 * MM], ent[2 * MM];
    __shared__ float scw[2 * 64];
    __shared__ float scp[2][2][64];
    __shared__ float aw[D], gw[D];
    __shared__ float redg[4];
    __shared__ float gateS[2];
    __shared__ float oth[D];

    int bid = blockIdx.x;
    int item = bid >> 1;
    int side = bid & 1;
    int t = threadIdx.x;

    const int* cA; const int* cB; int selfid; float* outp; bool isq;
    if (item < NB) {
        isq = true;
        cA = (side ? q_r1 : q_l1) + (size_t)item * MM * 2;
        cB = (side ? q_r2 : q_l2) + (size_t)item * MM * 2;
        selfid = query[item * 2 + side];
        outp = qv + (size_t)item * DM + side * D;
    } else {
        isq = false;
        int i2 = item - NB;
        cA = (side ? s_r1 : s_l1) + (size_t)i2 * MM * 2;
        cB = (side ? s_r2 : s_l2) + (size_t)i2 * MM * 2;
        selfid = support[i2 * 2 + side];
        outp = sv + (size_t)i2 * DM + side * D;
    }
    if (t < D) { aw[t] = attn_W[t]; gw[t] = gate_W[t]; }
    if (t < 2 * MM) {
        const int* c = (t < MM) ? cA : cB;
        int m = (t < MM) ? t : t - MM;
        rel[t] = c[m * 2]; ent[t] = c[m * 2 + 1];
    }
    __syncthreads();
    // gather + leakyrelu -> bf16 LDS, 16B loads
    for (int e8 = t; e8 < 2 * MM * 16; e8 += 256) {
        int m = e8 >> 4, d8 = (e8 & 15) * 8;
        short8 a = *(const short8*)(P1 + (size_t)rel[m] * D + d8);
        short8 b = *(const short8*)(P2 + (size_t)ent[m] * D + d8);
        short8 o;
        #pragma unroll
        for (int j = 0; j < 8; ++j) {
            float p = bf2f((unsigned short)a[j]) + bf2f((unsigned short)b[j]);
            p = (p >= 0.f) ? p : 0.01f * p;
            o[j] = (short)f2bf(p);
        }
        *(short8*)(proj + m * 136 + d8) = o;
    }
    __syncthreads();
    {
        int tab = t >> 7, g = (t >> 6) & 1, m = t & 63;
        float s = 0.f;
        if (m < MM) {
            const unsigned short* pr = proj + (tab * MM + m) * 136 + g * 64;
            #pragma unroll
            for (int i = 0; i < 8; ++i) {
                short8 v8 = *(const short8*)(pr + i * 8);
                #pragma unroll
                for (int j = 0; j < 8; ++j)
                    s += bf2f((unsigned short)v8[j]) * aw[g * 64 + i * 8 + j];
            }
        }
        scp[tab][g][m] = s;
    }
    __syncthreads();
    if (t < 128) {
        int tab = t >> 6, m = t & 63;
        float v = (m < MM) ? (scp[tab][0][m] + scp[tab][1][m] + attn_b[0]) : -1e30f;
        float mx = v;
        #pragma unroll
        for (int o = 32; o > 0; o >>= 1) mx = fmaxf(mx, __shfl_xor(mx, o, 64));
        float ev = (m < MM) ? __expf(v - mx) : 0.f;
        float sm = ev;
        #pragma unroll
        for (int o = 32; o > 0; o >>= 1) sm += __shfl_xor(sm, o, 64);
        if (m < MM) scw[tab * 64 + m] = ev / sm;
    }
    __syncthreads();
    int tab = t >> 7, d = t & 127;
    float agg = 0.f;
    #pragma unroll 5
    for (int m = 0; m < MM; ++m)
        agg += scw[tab * 64 + m] * bf2f(proj[(tab * MM + m) * 136 + d]);
    float gpart = agg * gw[d];
    #pragma unroll
    for (int o = 32; o > 0; o >>= 1) gpart += __shfl_xor(gpart, o, 64);
    if ((t & 63) == 0) redg[t >> 6] = gpart;
    __syncthreads();
    if (t == 0)  gateS[0] = sigf(redg[0] + redg[1] + gate_lb[0] + gate_b[0]);
    if (t == 64) gateS[1] = sigf(redg[2] + redg[3] + gate_lb[0] + gate_b[0]);
    __syncthreads();
    float embd = emb[(size_t)selfid * D + d];
    float val = gateS[tab] * agg + (1.f - gateS[tab]) * embd;
    if (tab == 1) oth[d] = val;
    __syncthreads();
    if (tab == 0) {
        float r = 0.5f * (val + oth[d]);
        outp[d] = r;
        if (isq) qvbf[(size_t)item * DM + side * D + d] = f2bf(r);
    }
}

// ---------------------------------------------------------------------------
// Kernel 3: sv -> sg.  1024 threads, split-K phases (was 256-thread single
// block pulling 768 KB serially).
// ---------------------------------------------------------------------------
__global__ __launch_bounds__(1024) void k_sg(
    const float* __restrict__ sv,
    const float* __restrict__ p1_W, const float* __restrict__ p1_b,
    const float* __restrict__ p2_W, const float* __restrict__ p2_b,
    const float* __restrict__ ln_a, const float* __restrict__ ln_b,
    float* __restrict__ sg)
{
    __shared__ float s[DM];
    __shared__ float hid[2 * DM];
    __shared__ float p1p[2][2 * DM];
    __shared__ float p2p[4][DM];
    __shared__ float red[8];
    int t = threadIdx.x;
    if (t < DM) s[t] = sv[t];
    __syncthreads();
    {   // phase 1: hid[j] = relu(p1_W[j] . s + b); j = t&511, half = t>>9
        int j = t & 511, hh = t >> 9;
        const float* wr = p1_W + (size_t)j * DM + hh * 128;
        const float* sr = s + hh * 128;
        float a = 0.f;
        #pragma unroll 8
        for (int c = 0; c < 128; ++c) a += wr[c] * sr[c];
        p1p[hh][j] = a;
    }
    __syncthreads();
    if (t < 512) hid[t] = fmaxf(p1p[0][t] + p1p[1][t] + p1_b[t], 0.f);
    __syncthreads();
    {   // phase 2: h[j] = p2_W[j] . hid + b + s; j = t&255, quarter = t>>8
        int j = t & 255, q = t >> 8;
        const float* wr = p2_W + (size_t)j * 2 * DM + q * 128;
        const float* hr = hid + q * 128;
        float a = 0.f;
        #pragma unroll 8
        for (int c = 0; c < 128; ++c) a += wr[c] * hr[c];
        p2p[q][j] = a;
    }
    __syncthreads();
    if (t < DM) {
        float x = p2p[0][t] + p2p[1][t] + p2p[2][t] + p2p[3][t] + p2_b[t] + s[t];
        float sm = x;
        #pragma unroll
        for (int o = 32; o > 0; o >>= 1) sm += __shfl_xor(sm, o, 64);
        if ((t & 63) == 0) red[t >> 6] = sm;
        s[t] = x;    // stash h
    }
    __syncthreads();
    if (t < DM) {
        float mu = (red[0] + red[1] + red[2] + red[3]) * (1.0f / 256.0f);
        float dv = s[t] - mu;
        float sq = dv * dv;
        #pragma unroll
        for (int o = 32; o > 0; o >>= 1) sq += __shfl_xor(sq, o, 64);
        if ((t & 63) == 0) red[4 + (t >> 6)] = sq;
        p2p[0][t] = dv;
    }
    __syncthreads();
    if (t < DM) {
        float var = (red[4] + red[5] + red[6] + red[7]) * (1.0f / 255.0f);
        float sig = sqrtf(var);
        sg[t] = p2p[0][t] / (sig + 0.001f) * ln_a[t] + ln_b[t];
    }
}

// ---------------------------------------------------------------------------
// Kernel 4: sgW[k] = sg . Whh[k, 256:] ; also zeroes d_out (8 blocks x 512).
// ---------------------------------------------------------------------------
__global__ __launch_bounds__(256) void k_sgwhh(
    const float* __restrict__ sg, const float* __restrict__ Whh,
    float* __restrict__ sgW, float* __restrict__ out)
{
    __shared__ float s[DM];
    int t = threadIdx.x;
    if (t < DM) s[t] = sg[t];
    __syncthreads();
    int k = blockIdx.x * 256 + t;
    const float* w = Whh + (size_t)k * HSZ + DM;
    float a = 0.f;
    #pragma unroll 4
    for (int j = 0; j < DM; ++j) a += w[j] * s[j];
    sgW[k] = a;
    out[blockIdx.x * 512 + t] = 0.f;
    out[blockIdx.x * 512 + 256 + t] = 0.f;
}

// ---------------------------------------------------------------------------
// Kernel 5: fused LSTM step via MFMA.  Block = 64 batch rows (halves B-read
// vs round-6's 32); wave w owns column tile T = blockIdx.y*4 + w and its gate
// tiles T+32g.  Cf / g0 in canonical fragment layout (grid-independent):
//   Cf  [(T*256 + bchunk)*64 + lane]          float4
//   g0f [((g*32+T)*256 + bchunk)*64 + lane]*4 ushort4
// where bchunk = b0/16 + mt.  hq ping-pongs across launches (race fix, r6).
// ---------------------------------------------------------------------------
__global__ __launch_bounds__(256) void k_lstm(
    const float* __restrict__ qv, const unsigned short* __restrict__ Ain,
    const unsigned short* __restrict__ Bp,
    const float* __restrict__ gb, const float* __restrict__ sgW,
    const unsigned short* __restrict__ g0i, unsigned short* __restrict__ g0o,
    float4* __restrict__ Cf, unsigned short* __restrict__ hqo,
    const float* __restrict__ sg, float* __restrict__ out, int mode)
{
    int t = threadIdx.x;
    int lane = t & 63, w = t >> 6;
    int nl = lane & 15, quad = lane >> 4;
    int bx = blockIdx.x;
    int b0 = bx * 64;
    int T = blockIdx.y * 4 + w;

    floatx4 acc[4][4];
    #pragma unroll
    for (int mt = 0; mt < 4; ++mt)
        #pragma unroll
        for (int g = 0; g < 4; ++g) acc[mt][g] = (floatx4){0.f, 0.f, 0.f, 0.f};

    for (int ks = 0; ks < 8; ++ks) {
        short8 af[4];
        #pragma unroll
        for (int mt = 0; mt < 4; ++mt)
            af[mt] = *(const short8*)(Ain + (size_t)(b0 + mt * 16 + nl) * DM + ks * 32 + quad * 8);
        #pragma unroll
        for (int g = 0; g < 4; ++g) {
            short8 bfr = *(const short8*)(Bp + ((size_t)((T + 32 * g) * 8 + ks) * 64 + lane) * 8);
            #pragma unroll
            for (int mt = 0; mt < 4; ++mt)
                acc[mt][g] = __builtin_amdgcn_mfma_f32_16x16x32_bf16(af[mt], bfr, acc[mt][g], 0, 0, 0);
        }
    }

    int coli = T * 16 + nl;
    #pragma unroll
    for (int mt = 0; mt < 4; ++mt) {
        int bchunk = bx * 4 + mt;
        size_t cfi = ((size_t)T * 256 + bchunk) * 64 + lane;
        if (mode == 0) {
            float bi = gb[coli], bff = gb[coli + 512];
            float bg = gb[coli + 1024], bo = gb[coli + 1536];
            float4 cn4; ushort4 pk[4];
            #pragma unroll
            for (int r = 0; r < 4; ++r) {
                float gi_ = acc[mt][0][r] + bi;
                float gf_ = acc[mt][1][r] + bff;
                float gg_ = acc[mt][2][r] + bg;
                float go_ = acc[mt][3][r] + bo;
                float cn = sigf(gi_) * tanhfast(gg_);
                (&cn4.x)[r] = cn;
                ((unsigned short*)&pk[0])[r] = f2bf(gi_);
                ((unsigned short*)&pk[1])[r] = f2bf(gf_);
                ((unsigned short*)&pk[2])[r] = f2bf(gg_);
                ((unsigned short*)&pk[3])[r] = f2bf(go_);
                if (T < 16) {
                    int b = b0 + mt * 16 + quad * 4 + r;
                    float h = qv[(size_t)b * DM + coli] + sigf(go_) * tanhfast(cn);
                    hqo[(size_t)b * DM + coli] = f2bf(h);
                }
            }
            #pragma unroll
            for (int g = 0; g < 4; ++g) {
                size_t gfi = (((size_t)(g * 32 + T) * 256 + bchunk) * 64 + lane) * 4;
                *(ushort4*)(g0o + gfi) = pk[g];
            }
            Cf[cfi] = cn4;
        } else {
            float si = sgW[coli], sf = sgW[coli + 512];
            float sgg = sgW[coli + 1024], so = sgW[coli + 1536];
            ushort4 gld[4];
            #pragma unroll
            for (int g = 0; g < 4; ++g) {
                size_t gfi = (((size_t)(g * 32 + T) * 256 + bchunk) * 64 + lane) * 4;
                gld[g] = *(const ushort4*)(g0i + gfi);
            }
            float4 cold = Cf[cfi];
            float4 cn4;
            float preg[4];
            #pragma unroll
            for (int r = 0; r < 4; ++r) {
                float gi_ = acc[mt][0][r] + si  + bf2f(((unsigned short*)&gld[0])[r]);
                float gf_ = acc[mt][1][r] + sf  + bf2f(((unsigned short*)&gld[1])[r]);
                float gg_ = acc[mt][2][r] + sgg + bf2f(((unsigned short*)&gld[2])[r]);
                float go_ = acc[mt][3][r] + so  + bf2f(((unsigned short*)&gld[3])[r]);
                float cn = sigf(gf_) * (&cold.x)[r] + sigf(gi_) * tanhfast(gg_);
                (&cn4.x)[r] = cn;
                preg[r] = 0.f;
                if (T < 16) {
                    int b = b0 + mt * 16 + quad * 4 + r;
                    float h = qv[(size_t)b * DM + coli] + sigf(go_) * tanhfast(cn);
                    if (mode == 1) hqo[(size_t)b * DM + coli] = f2bf(h);
                    else           preg[r] = h * sg[coli];
                }
            }
            if (mode == 1) Cf[cfi] = cn4;
            else {
                #pragma unroll
                for (int r = 0; r < 4; ++r) {
                    float p = preg[r];
                    p += __shfl_xor(p, 1, 64);
                    p += __shfl_xor(p, 2, 64);
                    p += __shfl_xor(p, 4, 64);
                    p += __shfl_xor(p, 8, 64);
                    if (nl == 0)
                        atomicAdd(out + b0 + mt * 16 + quad * 4 + r, p);
                }
            }
        }
    }
}

// ---------------------------------------------------------------------------
extern "C" void kernel_launch(void* const* d_in, const int* in_sizes, int n_in,
                              void* d_out, int out_size, void* d_ws, size_t ws_size,
                              hipStream_t stream) {
    const int* query   = (const int*)d_in[0];
    const int* support = (const int*)d_in[1];
    const int* q_l1 = (const int*)d_in[2];
    const int* q_l2 = (const int*)d_in[3];
    const int* q_r1 = (const int*)d_in[5];
    const int* q_r2 = (const int*)d_in[6];
    const int* s_l1 = (const int*)d_in[8];
    const int* s_l2 = (const int*)d_in[9];
    const int* s_r1 = (const int*)d_in[11];
    const int* s_r2 = (const int*)d_in[12];
    const float* emb    = (const float*)d_in[14];
    const float* gcn_W  = (const float*)d_in[15];
    const float* gcn_lb = (const float*)d_in[16];
    const float* gcn_b  = (const float*)d_in[17];
    const float* attn_W = (const float*)d_in[18];
    const float* attn_b = (const float*)d_in[19];
    const float* gate_W = (const float*)d_in[20];
    const float* gate_lb = (const float*)d_in[21];
    const float* gate_b  = (const float*)d_in[22];
    const float* p1_W = (const float*)d_in[23];
    const float* p1_b = (const float*)d_in[24];
    const float* p2_W = (const float*)d_in[25];
    const float* p2_b = (const float*)d_in[26];
    const float* ln_a = (const float*)d_in[27];
    const float* ln_b = (const float*)d_in[28];
    const float* Wih  = (const float*)d_in[29];
    const float* Whh  = (const float*)d_in[30];
    const float* bih  = (const float*)d_in[31];
    const float* bhh  = (const float*)d_in[32];

    // workspace layout: bf16 buffers first, then fp32 (16B-aligned blocks)
    unsigned short* P1   = (unsigned short*)d_ws;               // (V+1)*128
    unsigned short* P2   = P1 + (size_t)(VSZ + 1) * D;
    unsigned short* Wb   = P2 + (size_t)(VSZ + 1) * D;          // 256*128
    unsigned short* Wihp = Wb + 256 * 128;                      // 65536*8
    unsigned short* Whhp = Wihp + (size_t)65536 * 8;            // 65536*8
    unsigned short* g0b  = Whhp + (size_t)65536 * 8;            // NB*2048 (frag)
    unsigned short* hqA  = g0b + (size_t)NB * G4;               // NB*256
    unsigned short* hqB  = hqA + (size_t)NB * DM;               // NB*256
    unsigned short* qvbf = hqB + (size_t)NB * DM;               // NB*256
    float* fws = (float*)(qvbf + (size_t)NB * DM);
    float* gbv = fws;  fws += G4;
    float* qvb = fws;  fws += (size_t)NB * DM;                  // 4 MB
    float* svb = fws;  fws += DM;
    float* sgb = fws;  fws += DM;
    float* sgW = fws;  fws += G4 + 4;   // keep next block 16B-aligned
    float4* Cf = (float4*)fws;  fws += (size_t)NB * HSZ;        // 8 MB (frag)
    (void)in_sizes; (void)n_in; (void)out_size; (void)ws_size;

    k_pack<<<(131072 + 2048 + 32768) / 256, 256, 0, stream>>>(
        Wih, Whh, bih, bhh, gcn_W, Wihp, Whhp, gbv, Wb);
    k_proj_mfma<<<1024, 256, 0, stream>>>(
        emb, Wb, gcn_lb, gcn_b, P1, P2, VSZ + 1);
    k_nbr<<<2 * (NB + 1), 256, 0, stream>>>(
        query, support, q_l1, q_l2, q_r1, q_r2, s_l1, s_l2, s_r1, s_r2,
        P1, P2, emb, attn_W, attn_b, gate_W, gate_lb, gate_b, qvb, qvbf, svb);
    k_sg<<<1, 1024, 0, stream>>>(svb, p1_W, p1_b, p2_W, p2_b, ln_a, ln_b, sgb);
    k_sgwhh<<<G4 / 256, 256, 0, stream>>>(sgb, Whh, sgW, (float*)d_out);
    // step 1 (h_r = 0): A = qv bf16, B = Wih; write hqA
    k_lstm<<<dim3(NB / 64, 8), 256, 0, stream>>>(
        qvb, qvbf, Wihp, gbv, sgW, g0b, g0b, Cf, hqA, sgb, (float*)d_out, 0);
    // step 2: read hqA, write hqB
    k_lstm<<<dim3(NB / 64, 8), 256, 0, stream>>>(
        qvb, hqA, Whhp, gbv, sgW, g0b, g0b, Cf, hqB, sgb, (float*)d_out, 1);
    // step 3: read hqB, write hqA
    k_lstm<<<dim3(NB / 64, 8), 256, 0, stream>>>(
        qvb, hqB, Whhp, gbv, sgW, g0b, g0b, Cf, hqA, sgb, (float*)d_out, 1);
    // step 4: read hqA; only T<16 contribute -> y<4; atomic dot into out
    k_lstm<<<dim3(NB / 64, 4), 256, 0, stream>>>(
        qvb, hqA, Whhp, gbv, sgW, g0b, g0b, Cf, hqB, sgb, (float*)d_out, 2);
}